// Round 10
// baseline (7253.307 us; speedup 1.0000x reference)
//
#include <hip/hip_runtime.h>
#include <math.h>

#define BGRAPH 16
#define NPG    4096
#define NPTS   (BGRAPH*NPG)   // 65536
#define KNN    20
#define NC     40
#define EPSBN  1e-5f
#define SEG    4
#define CPTS   4              // points per conv1 block (80 edges = 5 M-tiles)

typedef _Float16 half8 __attribute__((ext_vector_type(8)));
typedef _Float16 h4 __attribute__((ext_vector_type(4)));
typedef _Float16 h2 __attribute__((ext_vector_type(2)));
typedef unsigned short ushort8 __attribute__((ext_vector_type(8)));
typedef float f32x4 __attribute__((ext_vector_type(4)));
typedef unsigned long long u64;

// ---------------- ws layout (bytes) ----------------
#define O_X0   0u               // float[NPTS*4]      1 MB
#define O_IDX  1048576u         // int[NPTS*20]       5 MB
#define O_X1   6291456u         // float[NPTS*64]     16 MB
#define O_UV   23068672u        // float[NPTS*256]    64 MB (knn packed partial lists overlay this)
#define O_WT   90177536u        // folded weights + out2enc + Wlh + s2g + W2t/W3t

// ---------------- helpers ----------------
__device__ __forceinline__ unsigned encf(float v) {
    unsigned u = __float_as_uint(v);
    return (u & 0x80000000u) ? ~u : (u | 0x80000000u);
}
__device__ __forceinline__ float decf(unsigned k) {
    unsigned u = (k & 0x80000000u) ? (k ^ 0x80000000u) : ~k;
    return __uint_as_float(u);
}
__device__ __forceinline__ unsigned ordf(float f) {
    unsigned u = __float_as_uint(f);
    return u ^ (((unsigned)((int)u >> 31)) | 0x80000000u);
}
// deterministic distance: identical instruction sequence at every use site
__device__ __forceinline__ float distf(float4 xi, float sqi, float4 xj, float sqj) {
    float dot = xi.x * xj.x;
    dot = fmaf(xi.y, xj.y, dot);
    dot = fmaf(xi.z, xj.z, dot);
    dot = fmaf(xi.w, xj.w, dot);
    return fmaf(-2.0f, dot, sqi + sqj);
}
__device__ __forceinline__ unsigned uminu(unsigned a, unsigned b) { return a < b ? a : b; }
// hardware 3-input median (exact sorted-insert primitive)
__device__ __forceinline__ unsigned umed3(unsigned a, unsigned b, unsigned c) {
    unsigned d;
    asm("v_med3_u32 %0, %1, %2, %3" : "=v"(d) : "v"(a), "v"(b), "v"(c));
    return d;
}

// 20-slot chain: w19 best (smallest) .. w0 = 20th smallest (tau).
// med3 insertion: w_i' = med3(w_{i+1}, w_i, c) (uses OLD values, depth-1), w19' = min(w19, c).
#define TK_DECL unsigned w0=0xFFFFFFFFu,w1=0xFFFFFFFFu,w2=0xFFFFFFFFu,w3=0xFFFFFFFFu,w4=0xFFFFFFFFu, \
    w5=0xFFFFFFFFu,w6=0xFFFFFFFFu,w7=0xFFFFFFFFu,w8=0xFFFFFFFFu,w9=0xFFFFFFFFu, \
    w10=0xFFFFFFFFu,w11=0xFFFFFFFFu,w12=0xFFFFFFFFu,w13=0xFFFFFFFFu,w14=0xFFFFFFFFu, \
    w15=0xFFFFFFFFu,w16=0xFFFFFFFFu,w17=0xFFFFFFFFu,w18=0xFFFFFFFFu,w19=0xFFFFFFFFu;
#define TK_INSERT(uv_) { unsigned cu = (uv_); \
    w0  = umed3(w1,  w0,  cu); \
    w1  = umed3(w2,  w1,  cu); \
    w2  = umed3(w3,  w2,  cu); \
    w3  = umed3(w4,  w3,  cu); \
    w4  = umed3(w5,  w4,  cu); \
    w5  = umed3(w6,  w5,  cu); \
    w6  = umed3(w7,  w6,  cu); \
    w7  = umed3(w8,  w7,  cu); \
    w8  = umed3(w9,  w8,  cu); \
    w9  = umed3(w10, w9,  cu); \
    w10 = umed3(w11, w10, cu); \
    w11 = umed3(w12, w11, cu); \
    w12 = umed3(w13, w12, cu); \
    w13 = umed3(w14, w13, cu); \
    w14 = umed3(w15, w14, cu); \
    w15 = umed3(w16, w15, cu); \
    w16 = umed3(w17, w16, cu); \
    w17 = umed3(w18, w17, cu); \
    w18 = umed3(w19, w18, cu); \
    w19 = uminu(w19, cu); }

// ---------------- K_prep: fused x0-build + Wl transpose + BN fold + W2t/W3t ------------
__global__ __launch_bounds__(256) void k_prep(
        const float* __restrict__ pos, const float* __restrict__ feat,
        const float* __restrict__ Wl,
        const float* __restrict__ W1, const float* __restrict__ b1,
        const float* __restrict__ g1, const float* __restrict__ be1,
        const float* __restrict__ m1, const float* __restrict__ v1,
        const float* __restrict__ W2, const float* __restrict__ b2,
        const float* __restrict__ g2, const float* __restrict__ be2,
        const float* __restrict__ m2, const float* __restrict__ v2,
        const float* __restrict__ W3, const float* __restrict__ Wc,
        float* __restrict__ x0, _Float16* __restrict__ Wlh,
        float* __restrict__ W1f, float* __restrict__ b1f,
        float* __restrict__ b2f,
        _Float16* __restrict__ W2t, _Float16* __restrict__ W3t,
        float* __restrict__ Wuv, unsigned* __restrict__ out2enc)
{
    __shared__ float tile[32][33];
    int bx = blockIdx.x, t = threadIdx.x;
    if (bx < 256) {                       // x0 = [pos | feat]
        int i = bx*256 + t;
        float4 v;
        v.x = pos[i*3+0]; v.y = pos[i*3+1]; v.z = pos[i*3+2]; v.w = feat[i];
        ((float4*)x0)[i] = v;
    } else if (bx < 256 + 192) {          // Wlh[j][k] = fp16(Wl[k][j])
        int w = bx - 256;
        int jb = (w & 31) * 32, kb = (w >> 5) * 32;
        int tx = t & 31, ty = t >> 5;
        #pragma unroll
        for (int r = 0; r < 32; r += 8)
            tile[ty + r][tx] = Wl[(size_t)(kb + ty + r)*1024 + jb + tx];
        __syncthreads();
        #pragma unroll
        for (int r = 0; r < 32; r += 8)
            Wlh[(size_t)(jb + ty + r)*192 + kb + tx] = (_Float16)tile[tx][ty + r];
    } else if (bx == 448) {               // BN fold + Wuv + pool-accumulator zero
        for (int i = t; i < 64; i += 256) {
            float s1 = g1[i] * rsqrtf(v1[i] + EPSBN);
            b1f[i] = (b1[i] - m1[i]) * s1 + be1[i];
            float s2 = g2[i] * rsqrtf(v2[i] + EPSBN);
            b2f[i] = (b2[i] - m2[i]) * s2 + be2[i];
        }
        for (int i = t; i < 8*64; i += 256) {
            int c = i & 63;
            W1f[i] = W1[i] * (g1[c] * rsqrtf(v1[c] + EPSBN));
        }
        for (int i = t; i < 64*256; i += 256) {
            int d = i >> 8, c = i & 255;
            Wuv[i] = (c < 128) ? (Wc[d*128 + c] - Wc[(64+d)*128 + c])
                               : Wc[(64+d)*128 + (c - 128)];
        }
        for (int i = t; i < 16*1024; i += 256) out2enc[i] = 0u;
    } else {                              // bx == 449: W2t/W3t = fp16 transposed (+BN fold on W2)
        for (int i = t; i < 4096; i += 256) {
            int n = i & 63, k = i >> 6;
            float s2 = g2[n] * rsqrtf(v2[n] + EPSBN);
            W2t[(size_t)n*64 + k] = (_Float16)(W2[(size_t)k*64 + n] * s2);
            W3t[(size_t)n*64 + k] = (_Float16)W3[(size_t)k*64 + n];
        }
    }
}

// ---------------- K1a: segmented kNN partials (med3 chain + single recovery pass) --------
__global__ __launch_bounds__(256, 2) void k_knn_part(const float* __restrict__ x0,
        u64* __restrict__ pk)
{
    __shared__ float4 pts[1024];
    __shared__ float  sqs[1024];
    int x  = blockIdx.x;
    int b  = x >> 6;
    int rb = (x >> 2) & 15;
    int s  = x & 3;
    int t  = threadIdx.x;
    int r  = b*NPG + rb*256 + t;
    float4 xi = ((const float4*)x0)[r];
    float sqi = xi.x*xi.x + xi.y*xi.y + xi.z*xi.z + xi.w*xi.w;
    #pragma unroll
    for (int l = 0; l < 4; ++l) {
        float4 v = ((const float4*)x0)[b*NPG + s*1024 + l*256 + t];
        pts[l*256 + t] = v;
        sqs[l*256 + t] = v.x*v.x + v.y*v.y + v.z*v.z + v.w*v.w;
    }
    __syncthreads();

    TK_DECL
    for (int j = 0; j < 1024; ++j) {
        float d = distf(xi, sqi, pts[j], sqs[j]);
        unsigned u = ordf(d);
        TK_INSERT(u)
    }
    unsigned tauU = w0;   // 20th smallest (orderable u32) in this segment

    int jbase = b*NPG + s*1024;
    u64* pcol = pk + (size_t)s*KNN*NPTS + r;
    unsigned cnt = 0, ecnt = 0;
    int e0 = 0, e1 = 0;
    #pragma unroll 1
    for (int j = 0; j < 1024; ++j) {
        float d = distf(xi, sqi, pts[j], sqs[j]);
        unsigned u = ordf(d);
        if (u < tauU) {
            pcol[(size_t)cnt*NPTS] = ((u64)u << 32) | (unsigned)(jbase + j);
            cnt++;
        } else if (u == tauU) {
            if (ecnt == 0) e0 = j; else if (ecnt == 1) e1 = j;
            ecnt++;
        }
    }
    if (cnt < KNN && ecnt > 0) { pcol[(size_t)cnt*NPTS] = ((u64)tauU << 32) | (unsigned)(jbase + e0); cnt++; }
    if (cnt < KNN && ecnt > 1) { pcol[(size_t)cnt*NPTS] = ((u64)tauU << 32) | (unsigned)(jbase + e1); cnt++; }
    while (cnt < KNN) {
        pcol[(size_t)cnt*NPTS] = ((u64)0xFFFFFFFFu << 32) | (unsigned)r;
        cnt++;
    }
}

// ---------------- K1b: merge 4 partial lists -> final 20 indices (set only) --------
__global__ __launch_bounds__(256, 2) void k_knn_merge(const u64* __restrict__ pk,
        int* __restrict__ idx)
{
    int r = blockIdx.x*256 + threadIdx.x;
    const unsigned* ph = (const unsigned*)pk;   // hi word (ordf value) of slot q

    TK_DECL
    #pragma unroll 4
    for (int q = 0; q < SEG*KNN; ++q) {
        unsigned u = ph[((size_t)q*NPTS + r)*2 + 1];
        TK_INSERT(u)
    }
    unsigned tauU = w0;

    unsigned cnt = 0;
    int* o = idx + (size_t)r*KNN;
    for (int q = 0; q < SEG*KNN; ++q) {
        u64 key = pk[(size_t)q*NPTS + r];
        unsigned u = (unsigned)(key >> 32);
        if (u < tauU && cnt < KNN) { o[cnt] = (int)(unsigned)key; cnt++; }
    }
    for (int q = 0; q < SEG*KNN; ++q) {
        u64 key = pk[(size_t)q*NPTS + r];
        unsigned u = (unsigned)(key >> 32);
        if (u == tauU && cnt < KNN) { o[cnt] = (int)(unsigned)key; cnt++; }
    }
    while (cnt < KNN) { o[cnt] = r; cnt++; }
}

// ---------------- K2: EdgeConv1 via MFMA ----------------
// Block: 256 thr (4 waves) = 4 points = 80 edges = 5 M-tiles of 16.
// L1 per-wave-per-point -> hs0[80][72] fp16; L2/L3 = mfma_f32_16x16x32_f16 with
// B-frags (W2t/W3t, [out-col][k]) in VGPRs; h3 kept f32 in regs then LDS overlay; max over 20.
__global__ __launch_bounds__(256) void k_conv1(const float* __restrict__ x0,
        const int* __restrict__ idx,
        const float* __restrict__ W1f, const float* __restrict__ b1f,
        const _Float16* __restrict__ W2t, const float* __restrict__ b2f,
        const _Float16* __restrict__ W3t, const float* __restrict__ b3,
        float* __restrict__ x1)
{
    __shared__ _Float16 hsbuf[2*80*72];   // hs0 | hs1 ; f32 overlay for h3
    _Float16* hs0 = hsbuf;
    _Float16* hs1 = hsbuf + 80*72;
    int t = threadIdx.x;
    int w = t >> 6, l = t & 63;
    int lr = l & 15, lg = l >> 4;

    // B fragments: [nt][ks], 8 halves each (pattern identical to verified k_out1)
    half8 w2f[4][2], w3f[4][2];
    #pragma unroll
    for (int nt = 0; nt < 4; ++nt)
        #pragma unroll
        for (int ks = 0; ks < 2; ++ks) {
            w2f[nt][ks] = *(const half8*)&W2t[(size_t)(nt*16 + lr)*64 + ks*32 + lg*8];
            w3f[nt][ks] = *(const half8*)&W3t[(size_t)(nt*16 + lr)*64 + ks*32 + lg*8];
        }
    float b2v[4], b3v[4];
    #pragma unroll
    for (int nt = 0; nt < 4; ++nt) { b2v[nt] = b2f[nt*16 + lr]; b3v[nt] = b3[nt*16 + lr]; }

    // L1: wave w owns point i, lane = channel c
    {
        int c = l;
        float w1c[8];
        #pragma unroll
        for (int f = 0; f < 8; ++f) w1c[f] = W1f[f*64 + c];
        float b1c = b1f[c];
        int i = blockIdx.x*CPTS + w;
        float4 xi = ((const float4*)x0)[i];
        #pragma unroll 4
        for (int k = 0; k < KNN; ++k) {
            int j = idx[i*KNN + k];
            float4 xj = ((const float4*)x0)[j];
            float h = b1c + xi.x*w1c[0] + xi.y*w1c[1] + xi.z*w1c[2] + xi.w*w1c[3]
                          + (xj.x-xi.x)*w1c[4] + (xj.y-xi.y)*w1c[5]
                          + (xj.z-xi.z)*w1c[6] + (xj.w-xi.w)*w1c[7];
            hs0[(w*KNN + k)*72 + c] = (_Float16)fmaxf(h, 0.0f);
        }
    }
    __syncthreads();

    // L2: hs1 = relu(hs0 @ W2 + b2)
    #pragma unroll
    for (int it = 0; it < 5; ++it) {
        int ti = w*5 + it, mt = ti >> 2, nt = ti & 3;
        f32x4 acc = {b2v[nt], b2v[nt], b2v[nt], b2v[nt]};
        #pragma unroll
        for (int ks = 0; ks < 2; ++ks) {
            half8 a = *(const half8*)&hs0[(mt*16 + lr)*72 + ks*32 + lg*8];
            acc = __builtin_amdgcn_mfma_f32_16x16x32_f16(a, w2f[nt][ks], acc, 0, 0, 0);
        }
        #pragma unroll
        for (int jj = 0; jj < 4; ++jj)
            hs1[(mt*16 + lg*4 + jj)*72 + nt*16 + lr] = (_Float16)fmaxf(acc[jj], 0.0f);
    }
    __syncthreads();

    // L3: h3 = hs1 @ W3 + b3 (f32 kept in registers)
    float h3r[5][4];
    #pragma unroll
    for (int it = 0; it < 5; ++it) {
        int ti = w*5 + it, mt = ti >> 2, nt = ti & 3;
        f32x4 acc = {b3v[nt], b3v[nt], b3v[nt], b3v[nt]};
        #pragma unroll
        for (int ks = 0; ks < 2; ++ks) {
            half8 a = *(const half8*)&hs1[(mt*16 + lr)*72 + ks*32 + lg*8];
            acc = __builtin_amdgcn_mfma_f32_16x16x32_f16(a, w3f[nt][ks], acc, 0, 0, 0);
        }
        #pragma unroll
        for (int jj = 0; jj < 4; ++jj) h3r[it][jj] = acc[jj];
    }
    __syncthreads();   // all reads of hsbuf done; safe to overlay f32

    float* h3f = (float*)hsbuf;   // [80][66] f32 = 21120 B <= 23040 B
    #pragma unroll
    for (int it = 0; it < 5; ++it) {
        int ti = w*5 + it, mt = ti >> 2, nt = ti & 3;
        #pragma unroll
        for (int jj = 0; jj < 4; ++jj)
            h3f[(mt*16 + lg*4 + jj)*66 + nt*16 + lr] = h3r[it][jj];
    }
    __syncthreads();

    // max over the 20 edges of point w, channel l
    {
        float m = -3.0e38f;
        #pragma unroll 4
        for (int k = 0; k < KNN; ++k)
            m = fmaxf(m, h3f[(w*KNN + k)*66 + l]);
        x1[(size_t)(blockIdx.x*CPTS + w)*64 + l] = m;
    }
}

// ---------------- K3: uv = x1 @ [Wu | Wv]  (u' gets +bc) ----------------
__global__ __launch_bounds__(256) void k_uv(const float* __restrict__ x1, const float* __restrict__ Wuv,
                                            const float* __restrict__ bc, float* __restrict__ uv)
{
    __shared__ float4 As[64*16];  // 64 rows x 64 cols of x1
    int m0 = blockIdx.x * 64;
    int t  = threadIdx.x;
    #pragma unroll
    for (int l = 0; l < 4; ++l) {
        int lin = l*256 + t;  // 0..1023
        As[lin] = ((const float4*)x1)[(size_t)m0*16 + lin];
    }
    __syncthreads();
    int c = t;  // 0..255
    float acc[64];
    #pragma unroll
    for (int p = 0; p < 64; ++p) acc[p] = 0.f;
    for (int dq = 0; dq < 16; ++dq) {
        float bv0 = Wuv[(dq*4+0)*256 + c];
        float bv1 = Wuv[(dq*4+1)*256 + c];
        float bv2 = Wuv[(dq*4+2)*256 + c];
        float bv3 = Wuv[(dq*4+3)*256 + c];
        #pragma unroll
        for (int p = 0; p < 64; ++p) {
            float4 a = As[p*16 + dq];
            acc[p] += a.x*bv0 + a.y*bv1 + a.z*bv2 + a.w*bv3;
        }
    }
    float badd = (c < 128) ? bc[c] : 0.0f;
    #pragma unroll
    for (int p = 0; p < 64; ++p)
        uv[(size_t)(m0+p)*256 + c] = acc[p] + badd;
}

// ---------------- K4: x2 = u' + max_k v[nbr]  (in-place into u' half of uv) ----------------
__global__ __launch_bounds__(256) void k_x2(const int* __restrict__ idx, float* __restrict__ uv)
{
    int p = blockIdx.x*2 + (threadIdx.x >> 7);
    int c = threadIdx.x & 127;
    float m = -3.0e38f;
    #pragma unroll
    for (int k = 0; k < KNN; ++k) {
        int j = idx[p*KNN + k];
        m = fmaxf(m, uv[(size_t)j*256 + 128 + c]);
    }
    uv[(size_t)p*256 + c] += m;
}

// ---------------- K5: out1 = [x1|x2] @ Wl (+bl) via fp16 MFMA, fused max-pool ------------
__global__ __launch_bounds__(256) void k_out1(const float* __restrict__ x1, const float* __restrict__ uv,
        const _Float16* __restrict__ Wlh, const float* __restrict__ bl, unsigned* __restrict__ out2enc)
{
    __shared__ _Float16 Asd[64][208];   // 416B row stride -> conflict-free b128 frags
    __shared__ _Float16 Bsd[128][208];
    int n0 = blockIdx.x * 128;
    int m0 = blockIdx.y * 64;
    int t  = threadIdx.x;

    {
        int row = t >> 2, sub = t & 3;
        const float* xr = x1 + (size_t)(m0 + row)*64;
        const float* ur = uv + (size_t)(m0 + row)*256;
        #pragma unroll
        for (int cc = 0; cc < 12; ++cc) {
            int col = sub*48 + cc*4;
            float4 v = (col < 64) ? *(const float4*)(xr + col)
                                  : *(const float4*)(ur + (col - 64));
            h4 hv;
            hv[0] = (_Float16)v.x; hv[1] = (_Float16)v.y;
            hv[2] = (_Float16)v.z; hv[3] = (_Float16)v.w;
            *(h4*)&Asd[row][col] = hv;
        }
    }
    {
        int j = t >> 1, hf = t & 1;
        const ushort8* src = (const ushort8*)(Wlh + (size_t)(n0 + j)*192 + hf*96);
        #pragma unroll
        for (int ch = 0; ch < 12; ++ch)
            *(ushort8*)&Bsd[j][hf*96 + ch*8] = src[ch];
    }
    __syncthreads();

    int w  = t >> 6, l = t & 63;
    int lr = l & 15, lg = l >> 4;
    f32x4 acc[8];
    #pragma unroll
    for (int f = 0; f < 8; ++f) acc[f] = (f32x4){0.f, 0.f, 0.f, 0.f};
    #pragma unroll 1
    for (int ks = 0; ks < 6; ++ks) {
        half8 a = *(const half8*)&Asd[w*16 + lr][ks*32 + lg*8];
        #pragma unroll
        for (int f = 0; f < 8; ++f) {
            half8 b = *(const half8*)&Bsd[f*16 + lr][ks*32 + lg*8];
            acc[f] = __builtin_amdgcn_mfma_f32_16x16x32_f16(a, b, acc[f], 0, 0, 0);
        }
    }
    float cmax[8];
    #pragma unroll
    for (int f = 0; f < 8; ++f) {
        float m = fmaxf(fmaxf(acc[f][0], acc[f][1]), fmaxf(acc[f][2], acc[f][3]));
        m = fmaxf(m, __shfl_xor(m, 16));
        m = fmaxf(m, __shfl_xor(m, 32));
        cmax[f] = m;
    }
    __syncthreads();
    float* red = (float*)&Asd[0][0];     // [4][128]
    if (l < 16) {
        #pragma unroll
        for (int f = 0; f < 8; ++f) red[w*128 + f*16 + l] = cmax[f];
    }
    __syncthreads();
    if (t < 128) {
        float m = fmaxf(fmaxf(red[t], red[128 + t]), fmaxf(red[256 + t], red[384 + t]));
        m += bl[n0 + t];
        int g = m0 >> 12;
        atomicMax(&out2enc[g*1024 + n0 + t], encf(m));
    }
}

// ---------------- K6a: head layer A (s2 = relu(out2 @ Wa + ba)), 32 blocks ----------------
__global__ __launch_bounds__(256) void k_headA(const unsigned* __restrict__ out2enc,
        const float* __restrict__ Wa, const float* __restrict__ ba, float* __restrict__ s2g)
{
    __shared__ float s1[1024];
    int g = blockIdx.x >> 1, half = blockIdx.x & 1;
    int t = threadIdx.x;
    for (int i = t; i < 1024; i += 256) s1[i] = decf(out2enc[g*1024 + i]);
    __syncthreads();
    int col = half*256 + t;
    float a0 = 0.f, a1 = 0.f, a2 = 0.f, a3 = 0.f;
    #pragma unroll 4
    for (int d = 0; d < 1024; d += 4) {
        a0 = fmaf(s1[d+0], Wa[(size_t)(d+0)*512 + col], a0);
        a1 = fmaf(s1[d+1], Wa[(size_t)(d+1)*512 + col], a1);
        a2 = fmaf(s1[d+2], Wa[(size_t)(d+2)*512 + col], a2);
        a3 = fmaf(s1[d+3], Wa[(size_t)(d+3)*512 + col], a3);
    }
    s2g[g*512 + col] = fmaxf(ba[col] + ((a0 + a1) + (a2 + a3)), 0.f);
}

// ---------------- K6b: head layers B/O + log_softmax, 16 blocks ----------------
__global__ __launch_bounds__(256) void k_headB(const float* __restrict__ s2g,
        const float* __restrict__ Wb, const float* __restrict__ bb,
        const float* __restrict__ Wo, const float* __restrict__ bo,
        float* __restrict__ out)
{
    __shared__ float s2[512];
    __shared__ float s3[256];
    __shared__ float sl[NC];
    int g = blockIdx.x, t = threadIdx.x;
    for (int i = t; i < 512; i += 256) s2[i] = s2g[g*512 + i];
    __syncthreads();
    {
        float a = bb[t];
        #pragma unroll 8
        for (int d = 0; d < 512; ++d) a += s2[d] * Wb[(size_t)d*256 + t];
        s3[t] = fmaxf(a, 0.f);
    }
    __syncthreads();
    if (t < NC) {
        float a = bo[t];
        #pragma unroll 8
        for (int d = 0; d < 256; ++d) a += s3[d] * Wo[d*NC + t];
        sl[t] = a;
    }
    __syncthreads();
    if (t < 64) {
        float v = (t < NC) ? sl[t] : -3.0e38f;
        float m = v;
        #pragma unroll
        for (int o2 = 32; o2 >= 1; o2 >>= 1) m = fmaxf(m, __shfl_xor(m, o2));
        float e = (t < NC) ? expf(sl[t] - m) : 0.f;
        float s = e;
        #pragma unroll
        for (int o2 = 32; o2 >= 1; o2 >>= 1) s += __shfl_xor(s, o2);
        float ls = logf(s) + m;
        if (t < NC) out[g*NC + t] = sl[t] - ls;
    }
}

// ---------------- launch ----------------
extern "C" void kernel_launch(void* const* d_in, const int* in_sizes, int n_in,
                              void* d_out, int out_size, void* d_ws, size_t ws_size,
                              hipStream_t stream)
{
    const float* pos  = (const float*)d_in[0];
    const float* feat = (const float*)d_in[1];
    const float* W1 = (const float*)d_in[2];
    const float* b1 = (const float*)d_in[3];
    const float* g1 = (const float*)d_in[4];
    const float* be1= (const float*)d_in[5];
    const float* m1 = (const float*)d_in[6];
    const float* v1 = (const float*)d_in[7];
    const float* W2 = (const float*)d_in[8];
    const float* b2 = (const float*)d_in[9];
    const float* g2 = (const float*)d_in[10];
    const float* be2= (const float*)d_in[11];
    const float* m2 = (const float*)d_in[12];
    const float* v2 = (const float*)d_in[13];
    const float* W3 = (const float*)d_in[14];
    const float* b3 = (const float*)d_in[15];
    const float* Wc = (const float*)d_in[16];
    const float* bc = (const float*)d_in[17];
    const float* Wl = (const float*)d_in[18];
    const float* bl = (const float*)d_in[19];
    const float* Wa = (const float*)d_in[20];
    const float* ba = (const float*)d_in[21];
    const float* Wb = (const float*)d_in[22];
    const float* bb = (const float*)d_in[23];
    const float* Wo = (const float*)d_in[24];
    const float* bo = (const float*)d_in[25];
    float* out = (float*)d_out;

    char* ws = (char*)d_ws;
    float* x0  = (float*)(ws + O_X0);
    int*   idx = (int*)  (ws + O_IDX);
    float* x1  = (float*)(ws + O_X1);
    float* uv  = (float*)(ws + O_UV);
    u64*   pk  = (u64*)  (ws + O_UV);   // packed knn partials overlay uv (dead until k_uv)
    float* W1f = (float*)(ws + O_WT);
    float* b1f = W1f + 512;
    float* W2f = b1f + 64;              // (unused by conv1-MFMA; region reserved)
    float* b2f = W2f + 4096;
    float* Wuv = b2f + 64;
    unsigned* out2enc = (unsigned*)(Wuv + 64*256);
    _Float16* Wlh = (_Float16*)(ws + O_WT + 262144);        // 1024x192 fp16 = 384 KB
    float* s2g = (float*)(ws + O_WT + 262144 + 393216);     // 16x512 f32 = 32 KB
    _Float16* W2t = (_Float16*)(ws + O_WT + 262144 + 393216 + 32768);  // 64x64 fp16
    _Float16* W3t = W2t + 4096;                                        // 64x64 fp16

    k_prep <<<450, 256, 0, stream>>>(pos, feat, Wl,
                                     W1,b1,g1,be1,m1,v1, W2,b2,g2,be2,m2,v2, W3, Wc,
                                     x0, Wlh, W1f,b1f,b2f, W2t,W3t, Wuv,out2enc);
    k_knn_part <<<BGRAPH*16*SEG, 256, 0, stream>>>(x0, pk);
    k_knn_merge<<<NPTS/256, 256, 0, stream>>>(pk, idx);
    k_conv1<<<NPTS/CPTS, 256, 0, stream>>>(x0, idx, W1f, b1f, W2t, b2f, W3t, b3, x1);
    k_uv   <<<NPTS/64, 256, 0, stream>>>(x1, Wuv, bc, uv);
    k_x2   <<<NPTS/2, 256, 0, stream>>>(idx, uv);
    dim3 g5(8, 1024);
    k_out1 <<<g5, 256, 0, stream>>>(x1, uv, Wlh, bl, out2enc);
    k_headA<<<BGRAPH*2, 256, 0, stream>>>(out2enc, Wa, ba, s2g);
    k_headB<<<BGRAPH, 256, 0, stream>>>(s2g, Wb, bb, Wo, bo, out);
}

// Round 11
// 843.436 us; speedup vs baseline: 8.5997x; 8.5997x over previous
//
#include <hip/hip_runtime.h>
#include <math.h>

#define BGRAPH 16
#define NPG    4096
#define NPTS   (BGRAPH*NPG)   // 65536
#define KNN    20
#define NC     40
#define EPSBN  1e-5f
#define SEG    4
#define CPTS   4              // points per conv1 block (80 edges = 5 M-tiles)

typedef _Float16 half8 __attribute__((ext_vector_type(8)));
typedef _Float16 h4 __attribute__((ext_vector_type(4)));
typedef _Float16 h2 __attribute__((ext_vector_type(2)));
typedef unsigned short ushort8 __attribute__((ext_vector_type(8)));
typedef float f32x4 __attribute__((ext_vector_type(4)));
typedef unsigned long long u64;

// ---------------- ws layout (bytes) ----------------
#define O_X0   0u               // float[NPTS*4]      1 MB
#define O_IDX  1048576u         // int[NPTS*20]       5 MB
#define O_X1   6291456u         // float[NPTS*64]     16 MB
#define O_UV   23068672u        // float[NPTS*256]    64 MB (knn packed partial lists overlay this)
#define O_WT   90177536u        // folded weights + out2enc + Wlh + s2g + W2t/W3t

// ---------------- helpers ----------------
__device__ __forceinline__ unsigned encf(float v) {
    unsigned u = __float_as_uint(v);
    return (u & 0x80000000u) ? ~u : (u | 0x80000000u);
}
__device__ __forceinline__ float decf(unsigned k) {
    unsigned u = (k & 0x80000000u) ? (k ^ 0x80000000u) : ~k;
    return __uint_as_float(u);
}
__device__ __forceinline__ unsigned ordf(float f) {
    unsigned u = __float_as_uint(f);
    return u ^ (((unsigned)((int)u >> 31)) | 0x80000000u);
}
// deterministic distance: identical instruction sequence at every use site
__device__ __forceinline__ float distf(float4 xi, float sqi, float4 xj, float sqj) {
    float dot = xi.x * xj.x;
    dot = fmaf(xi.y, xj.y, dot);
    dot = fmaf(xi.z, xj.z, dot);
    dot = fmaf(xi.w, xj.w, dot);
    return fmaf(-2.0f, dot, sqi + sqj);
}
__device__ __forceinline__ unsigned uminu(unsigned a, unsigned b) { return a < b ? a : b; }
// hardware 3-input median (exact sorted-insert primitive)
__device__ __forceinline__ unsigned umed3(unsigned a, unsigned b, unsigned c) {
    unsigned d;
    asm("v_med3_u32 %0, %1, %2, %3" : "=v"(d) : "v"(a), "v"(b), "v"(c));
    return d;
}

// 20-slot chain: w19 best (smallest) .. w0 = 20th smallest (tau).
// med3 insertion: w_i' = med3(w_{i+1}, w_i, c) (uses OLD values, depth-1), w19' = min(w19, c).
#define TK_DECL unsigned w0=0xFFFFFFFFu,w1=0xFFFFFFFFu,w2=0xFFFFFFFFu,w3=0xFFFFFFFFu,w4=0xFFFFFFFFu, \
    w5=0xFFFFFFFFu,w6=0xFFFFFFFFu,w7=0xFFFFFFFFu,w8=0xFFFFFFFFu,w9=0xFFFFFFFFu, \
    w10=0xFFFFFFFFu,w11=0xFFFFFFFFu,w12=0xFFFFFFFFu,w13=0xFFFFFFFFu,w14=0xFFFFFFFFu, \
    w15=0xFFFFFFFFu,w16=0xFFFFFFFFu,w17=0xFFFFFFFFu,w18=0xFFFFFFFFu,w19=0xFFFFFFFFu;
#define TK_INSERT(uv_) { unsigned cu = (uv_); \
    w0  = umed3(w1,  w0,  cu); \
    w1  = umed3(w2,  w1,  cu); \
    w2  = umed3(w3,  w2,  cu); \
    w3  = umed3(w4,  w3,  cu); \
    w4  = umed3(w5,  w4,  cu); \
    w5  = umed3(w6,  w5,  cu); \
    w6  = umed3(w7,  w6,  cu); \
    w7  = umed3(w8,  w7,  cu); \
    w8  = umed3(w9,  w8,  cu); \
    w9  = umed3(w10, w9,  cu); \
    w10 = umed3(w11, w10, cu); \
    w11 = umed3(w12, w11, cu); \
    w12 = umed3(w13, w12, cu); \
    w13 = umed3(w14, w13, cu); \
    w14 = umed3(w15, w14, cu); \
    w15 = umed3(w16, w15, cu); \
    w16 = umed3(w17, w16, cu); \
    w17 = umed3(w18, w17, cu); \
    w18 = umed3(w19, w18, cu); \
    w19 = uminu(w19, cu); }

// ---------------- K_prep: fused x0-build + Wl transpose + BN fold + W2t/W3t ------------
__global__ __launch_bounds__(256) void k_prep(
        const float* __restrict__ pos, const float* __restrict__ feat,
        const float* __restrict__ Wl,
        const float* __restrict__ W1, const float* __restrict__ b1,
        const float* __restrict__ g1, const float* __restrict__ be1,
        const float* __restrict__ m1, const float* __restrict__ v1,
        const float* __restrict__ W2, const float* __restrict__ b2,
        const float* __restrict__ g2, const float* __restrict__ be2,
        const float* __restrict__ m2, const float* __restrict__ v2,
        const float* __restrict__ W3, const float* __restrict__ Wc,
        float* __restrict__ x0, _Float16* __restrict__ Wlh,
        float* __restrict__ W1f, float* __restrict__ b1f,
        float* __restrict__ b2f,
        _Float16* __restrict__ W2t, _Float16* __restrict__ W3t,
        float* __restrict__ Wuv, unsigned* __restrict__ out2enc)
{
    __shared__ float tile[32][33];
    int bx = blockIdx.x, t = threadIdx.x;
    if (bx < 256) {                       // x0 = [pos | feat]
        int i = bx*256 + t;
        float4 v;
        v.x = pos[i*3+0]; v.y = pos[i*3+1]; v.z = pos[i*3+2]; v.w = feat[i];
        ((float4*)x0)[i] = v;
    } else if (bx < 256 + 192) {          // Wlh[j][k] = fp16(Wl[k][j])
        int w = bx - 256;
        int jb = (w & 31) * 32, kb = (w >> 5) * 32;
        int tx = t & 31, ty = t >> 5;
        #pragma unroll
        for (int r = 0; r < 32; r += 8)
            tile[ty + r][tx] = Wl[(size_t)(kb + ty + r)*1024 + jb + tx];
        __syncthreads();
        #pragma unroll
        for (int r = 0; r < 32; r += 8)
            Wlh[(size_t)(jb + ty + r)*192 + kb + tx] = (_Float16)tile[tx][ty + r];
    } else if (bx == 448) {               // BN fold + Wuv + pool-accumulator zero
        for (int i = t; i < 64; i += 256) {
            float s1 = g1[i] * rsqrtf(v1[i] + EPSBN);
            b1f[i] = (b1[i] - m1[i]) * s1 + be1[i];
            float s2 = g2[i] * rsqrtf(v2[i] + EPSBN);
            b2f[i] = (b2[i] - m2[i]) * s2 + be2[i];
        }
        for (int i = t; i < 8*64; i += 256) {
            int c = i & 63;
            W1f[i] = W1[i] * (g1[c] * rsqrtf(v1[c] + EPSBN));
        }
        for (int i = t; i < 64*256; i += 256) {
            int d = i >> 8, c = i & 255;
            Wuv[i] = (c < 128) ? (Wc[d*128 + c] - Wc[(64+d)*128 + c])
                               : Wc[(64+d)*128 + (c - 128)];
        }
        for (int i = t; i < 16*1024; i += 256) out2enc[i] = 0u;
    } else {                              // bx == 449: W2t/W3t = fp16 transposed (+BN fold on W2)
        for (int i = t; i < 4096; i += 256) {
            int n = i & 63, k = i >> 6;
            float s2 = g2[n] * rsqrtf(v2[n] + EPSBN);
            W2t[(size_t)n*64 + k] = (_Float16)(W2[(size_t)k*64 + n] * s2);
            W3t[(size_t)n*64 + k] = (_Float16)W3[(size_t)k*64 + n];
        }
    }
}

// ---------------- K1a: segmented kNN partials (med3 chain + single recovery pass) --------
__global__ __launch_bounds__(256, 2) void k_knn_part(const float* __restrict__ x0,
        u64* __restrict__ pk)
{
    __shared__ float4 pts[1024];
    __shared__ float  sqs[1024];
    int x  = blockIdx.x;
    int b  = x >> 6;
    int rb = (x >> 2) & 15;
    int s  = x & 3;
    int t  = threadIdx.x;
    int r  = b*NPG + rb*256 + t;
    float4 xi = ((const float4*)x0)[r];
    float sqi = xi.x*xi.x + xi.y*xi.y + xi.z*xi.z + xi.w*xi.w;
    #pragma unroll
    for (int l = 0; l < 4; ++l) {
        float4 v = ((const float4*)x0)[b*NPG + s*1024 + l*256 + t];
        pts[l*256 + t] = v;
        sqs[l*256 + t] = v.x*v.x + v.y*v.y + v.z*v.z + v.w*v.w;
    }
    __syncthreads();

    TK_DECL
    for (int j = 0; j < 1024; ++j) {
        float d = distf(xi, sqi, pts[j], sqs[j]);
        unsigned u = ordf(d);
        TK_INSERT(u)
    }
    unsigned tauU = w0;   // 20th smallest (orderable u32) in this segment

    int jbase = b*NPG + s*1024;
    u64* pcol = pk + (size_t)s*KNN*NPTS + r;
    unsigned cnt = 0, ecnt = 0;
    int e0 = 0, e1 = 0;
    #pragma unroll 1
    for (int j = 0; j < 1024; ++j) {
        float d = distf(xi, sqi, pts[j], sqs[j]);
        unsigned u = ordf(d);
        if (u < tauU) {
            pcol[(size_t)cnt*NPTS] = ((u64)u << 32) | (unsigned)(jbase + j);
            cnt++;
        } else if (u == tauU) {
            if (ecnt == 0) e0 = j; else if (ecnt == 1) e1 = j;
            ecnt++;
        }
    }
    if (cnt < KNN && ecnt > 0) { pcol[(size_t)cnt*NPTS] = ((u64)tauU << 32) | (unsigned)(jbase + e0); cnt++; }
    if (cnt < KNN && ecnt > 1) { pcol[(size_t)cnt*NPTS] = ((u64)tauU << 32) | (unsigned)(jbase + e1); cnt++; }
    while (cnt < KNN) {
        pcol[(size_t)cnt*NPTS] = ((u64)0xFFFFFFFFu << 32) | (unsigned)r;
        cnt++;
    }
}

// ---------------- K1b: merge 4 partial lists -> final 20 indices (set only) --------
__global__ __launch_bounds__(256, 2) void k_knn_merge(const u64* __restrict__ pk,
        int* __restrict__ idx)
{
    int r = blockIdx.x*256 + threadIdx.x;
    const unsigned* ph = (const unsigned*)pk;   // hi word (ordf value) of slot q

    TK_DECL
    #pragma unroll 4
    for (int q = 0; q < SEG*KNN; ++q) {
        unsigned u = ph[((size_t)q*NPTS + r)*2 + 1];
        TK_INSERT(u)
    }
    unsigned tauU = w0;

    unsigned cnt = 0;
    int* o = idx + (size_t)r*KNN;
    for (int q = 0; q < SEG*KNN; ++q) {
        u64 key = pk[(size_t)q*NPTS + r];
        unsigned u = (unsigned)(key >> 32);
        if (u < tauU && cnt < KNN) { o[cnt] = (int)(unsigned)key; cnt++; }
    }
    for (int q = 0; q < SEG*KNN; ++q) {
        u64 key = pk[(size_t)q*NPTS + r];
        unsigned u = (unsigned)(key >> 32);
        if (u == tauU && cnt < KNN) { o[cnt] = (int)(unsigned)key; cnt++; }
    }
    while (cnt < KNN) { o[cnt] = r; cnt++; }
}

// ---------------- K2: EdgeConv1 via MFMA (wave w owns output-column block nt = w) --------
// Block: 256 thr (4 waves) = 4 points = 80 edges = 5 M-tiles x 4 N-tiles.
// All register arrays indexed ONLY by compile-time constants (rule #20).
__global__ __launch_bounds__(256) void k_conv1(const float* __restrict__ x0,
        const int* __restrict__ idx,
        const float* __restrict__ W1f, const float* __restrict__ b1f,
        const _Float16* __restrict__ W2t, const float* __restrict__ b2f,
        const _Float16* __restrict__ W3t, const float* __restrict__ b3,
        float* __restrict__ x1)
{
    __shared__ _Float16 hsbuf[2*80*72];   // hs0 | hs1 ; f32 overlay for h3
    _Float16* hs0 = hsbuf;
    _Float16* hs1 = hsbuf + 80*72;
    int t = threadIdx.x;
    int w = t >> 6, l = t & 63;
    int lr = l & 15, lg = l >> 4;

    // This wave's B fragments: output cols [w*16, w*16+16), compile-time-indexed arrays only
    half8 w2f[2], w3f[2];
    #pragma unroll
    for (int ks = 0; ks < 2; ++ks) {
        w2f[ks] = *(const half8*)&W2t[(size_t)(w*16 + lr)*64 + ks*32 + lg*8];
        w3f[ks] = *(const half8*)&W3t[(size_t)(w*16 + lr)*64 + ks*32 + lg*8];
    }
    float b2s = b2f[w*16 + lr];
    float b3s = b3[w*16 + lr];

    // L1: wave w owns point i, lane = channel c
    {
        int c = l;
        float w1c[8];
        #pragma unroll
        for (int f = 0; f < 8; ++f) w1c[f] = W1f[f*64 + c];
        float b1c = b1f[c];
        int i = blockIdx.x*CPTS + w;
        float4 xi = ((const float4*)x0)[i];
        #pragma unroll 4
        for (int k = 0; k < KNN; ++k) {
            int j = idx[i*KNN + k];
            float4 xj = ((const float4*)x0)[j];
            float h = b1c + xi.x*w1c[0] + xi.y*w1c[1] + xi.z*w1c[2] + xi.w*w1c[3]
                          + (xj.x-xi.x)*w1c[4] + (xj.y-xi.y)*w1c[5]
                          + (xj.z-xi.z)*w1c[6] + (xj.w-xi.w)*w1c[7];
            hs0[(w*KNN + k)*72 + c] = (_Float16)fmaxf(h, 0.0f);
        }
    }
    __syncthreads();

    // L2: hs1 = relu(hs0 @ W2 + b2); wave w computes N-block w for all 5 M-tiles
    #pragma unroll
    for (int mt = 0; mt < 5; ++mt) {
        f32x4 acc = {b2s, b2s, b2s, b2s};
        #pragma unroll
        for (int ks = 0; ks < 2; ++ks) {
            half8 a = *(const half8*)&hs0[(mt*16 + lr)*72 + ks*32 + lg*8];
            acc = __builtin_amdgcn_mfma_f32_16x16x32_f16(a, w2f[ks], acc, 0, 0, 0);
        }
        #pragma unroll
        for (int jj = 0; jj < 4; ++jj)
            hs1[(mt*16 + lg*4 + jj)*72 + w*16 + lr] = (_Float16)fmaxf(acc[jj], 0.0f);
    }
    __syncthreads();

    // L3: h3 = hs1 @ W3 + b3 (f32 kept in registers; mt/jj compile-time)
    float h3r[5][4];
    #pragma unroll
    for (int mt = 0; mt < 5; ++mt) {
        f32x4 acc = {b3s, b3s, b3s, b3s};
        #pragma unroll
        for (int ks = 0; ks < 2; ++ks) {
            half8 a = *(const half8*)&hs1[(mt*16 + lr)*72 + ks*32 + lg*8];
            acc = __builtin_amdgcn_mfma_f32_16x16x32_f16(a, w3f[ks], acc, 0, 0, 0);
        }
        #pragma unroll
        for (int jj = 0; jj < 4; ++jj) h3r[mt][jj] = acc[jj];
    }
    __syncthreads();   // all reads of hsbuf done; safe to overlay f32

    float* h3f = (float*)hsbuf;   // [80][66] f32 = 21120 B <= 23040 B
    #pragma unroll
    for (int mt = 0; mt < 5; ++mt) {
        #pragma unroll
        for (int jj = 0; jj < 4; ++jj)
            h3f[(mt*16 + lg*4 + jj)*66 + w*16 + lr] = h3r[mt][jj];
    }
    __syncthreads();

    // max over the 20 edges of point w, channel l
    {
        float m = -3.0e38f;
        #pragma unroll 4
        for (int k = 0; k < KNN; ++k)
            m = fmaxf(m, h3f[(w*KNN + k)*66 + l]);
        x1[(size_t)(blockIdx.x*CPTS + w)*64 + l] = m;
    }
}

// ---------------- K3: uv = x1 @ [Wu | Wv]  (u' gets +bc) ----------------
__global__ __launch_bounds__(256) void k_uv(const float* __restrict__ x1, const float* __restrict__ Wuv,
                                            const float* __restrict__ bc, float* __restrict__ uv)
{
    __shared__ float4 As[64*16];  // 64 rows x 64 cols of x1
    int m0 = blockIdx.x * 64;
    int t  = threadIdx.x;
    #pragma unroll
    for (int l = 0; l < 4; ++l) {
        int lin = l*256 + t;  // 0..1023
        As[lin] = ((const float4*)x1)[(size_t)m0*16 + lin];
    }
    __syncthreads();
    int c = t;  // 0..255
    float acc[64];
    #pragma unroll
    for (int p = 0; p < 64; ++p) acc[p] = 0.f;
    for (int dq = 0; dq < 16; ++dq) {
        float bv0 = Wuv[(dq*4+0)*256 + c];
        float bv1 = Wuv[(dq*4+1)*256 + c];
        float bv2 = Wuv[(dq*4+2)*256 + c];
        float bv3 = Wuv[(dq*4+3)*256 + c];
        #pragma unroll
        for (int p = 0; p < 64; ++p) {
            float4 a = As[p*16 + dq];
            acc[p] += a.x*bv0 + a.y*bv1 + a.z*bv2 + a.w*bv3;
        }
    }
    float badd = (c < 128) ? bc[c] : 0.0f;
    #pragma unroll
    for (int p = 0; p < 64; ++p)
        uv[(size_t)(m0+p)*256 + c] = acc[p] + badd;
}

// ---------------- K4: x2 = u' + max_k v[nbr]  (in-place into u' half of uv) ----------------
__global__ __launch_bounds__(256) void k_x2(const int* __restrict__ idx, float* __restrict__ uv)
{
    int p = blockIdx.x*2 + (threadIdx.x >> 7);
    int c = threadIdx.x & 127;
    float m = -3.0e38f;
    #pragma unroll
    for (int k = 0; k < KNN; ++k) {
        int j = idx[p*KNN + k];
        m = fmaxf(m, uv[(size_t)j*256 + 128 + c]);
    }
    uv[(size_t)p*256 + c] += m;
}

// ---------------- K5: out1 = [x1|x2] @ Wl (+bl) via fp16 MFMA, fused max-pool ------------
__global__ __launch_bounds__(256) void k_out1(const float* __restrict__ x1, const float* __restrict__ uv,
        const _Float16* __restrict__ Wlh, const float* __restrict__ bl, unsigned* __restrict__ out2enc)
{
    __shared__ _Float16 Asd[64][208];   // 416B row stride -> conflict-free b128 frags
    __shared__ _Float16 Bsd[128][208];
    int n0 = blockIdx.x * 128;
    int m0 = blockIdx.y * 64;
    int t  = threadIdx.x;

    {
        int row = t >> 2, sub = t & 3;
        const float* xr = x1 + (size_t)(m0 + row)*64;
        const float* ur = uv + (size_t)(m0 + row)*256;
        #pragma unroll
        for (int cc = 0; cc < 12; ++cc) {
            int col = sub*48 + cc*4;
            float4 v = (col < 64) ? *(const float4*)(xr + col)
                                  : *(const float4*)(ur + (col - 64));
            h4 hv;
            hv[0] = (_Float16)v.x; hv[1] = (_Float16)v.y;
            hv[2] = (_Float16)v.z; hv[3] = (_Float16)v.w;
            *(h4*)&Asd[row][col] = hv;
        }
    }
    {
        int j = t >> 1, hf = t & 1;
        const ushort8* src = (const ushort8*)(Wlh + (size_t)(n0 + j)*192 + hf*96);
        #pragma unroll
        for (int ch = 0; ch < 12; ++ch)
            *(ushort8*)&Bsd[j][hf*96 + ch*8] = src[ch];
    }
    __syncthreads();

    int w  = t >> 6, l = t & 63;
    int lr = l & 15, lg = l >> 4;
    f32x4 acc[8];
    #pragma unroll
    for (int f = 0; f < 8; ++f) acc[f] = (f32x4){0.f, 0.f, 0.f, 0.f};
    #pragma unroll 1
    for (int ks = 0; ks < 6; ++ks) {
        half8 a = *(const half8*)&Asd[w*16 + lr][ks*32 + lg*8];
        #pragma unroll
        for (int f = 0; f < 8; ++f) {
            half8 b = *(const half8*)&Bsd[f*16 + lr][ks*32 + lg*8];
            acc[f] = __builtin_amdgcn_mfma_f32_16x16x32_f16(a, b, acc[f], 0, 0, 0);
        }
    }
    float cmax[8];
    #pragma unroll
    for (int f = 0; f < 8; ++f) {
        float m = fmaxf(fmaxf(acc[f][0], acc[f][1]), fmaxf(acc[f][2], acc[f][3]));
        m = fmaxf(m, __shfl_xor(m, 16));
        m = fmaxf(m, __shfl_xor(m, 32));
        cmax[f] = m;
    }
    __syncthreads();
    float* red = (float*)&Asd[0][0];     // [4][128]
    if (l < 16) {
        #pragma unroll
        for (int f = 0; f < 8; ++f) red[w*128 + f*16 + l] = cmax[f];
    }
    __syncthreads();
    if (t < 128) {
        float m = fmaxf(fmaxf(red[t], red[128 + t]), fmaxf(red[256 + t], red[384 + t]));
        m += bl[n0 + t];
        int g = m0 >> 12;
        atomicMax(&out2enc[g*1024 + n0 + t], encf(m));
    }
}

// ---------------- K6a: head layer A (s2 = relu(out2 @ Wa + ba)), 32 blocks ----------------
__global__ __launch_bounds__(256) void k_headA(const unsigned* __restrict__ out2enc,
        const float* __restrict__ Wa, const float* __restrict__ ba, float* __restrict__ s2g)
{
    __shared__ float s1[1024];
    int g = blockIdx.x >> 1, half = blockIdx.x & 1;
    int t = threadIdx.x;
    for (int i = t; i < 1024; i += 256) s1[i] = decf(out2enc[g*1024 + i]);
    __syncthreads();
    int col = half*256 + t;
    float a0 = 0.f, a1 = 0.f, a2 = 0.f, a3 = 0.f;
    #pragma unroll 4
    for (int d = 0; d < 1024; d += 4) {
        a0 = fmaf(s1[d+0], Wa[(size_t)(d+0)*512 + col], a0);
        a1 = fmaf(s1[d+1], Wa[(size_t)(d+1)*512 + col], a1);
        a2 = fmaf(s1[d+2], Wa[(size_t)(d+2)*512 + col], a2);
        a3 = fmaf(s1[d+3], Wa[(size_t)(d+3)*512 + col], a3);
    }
    s2g[g*512 + col] = fmaxf(ba[col] + ((a0 + a1) + (a2 + a3)), 0.f);
}

// ---------------- K6b: head layers B/O + log_softmax, 16 blocks ----------------
__global__ __launch_bounds__(256) void k_headB(const float* __restrict__ s2g,
        const float* __restrict__ Wb, const float* __restrict__ bb,
        const float* __restrict__ Wo, const float* __restrict__ bo,
        float* __restrict__ out)
{
    __shared__ float s2[512];
    __shared__ float s3[256];
    __shared__ float sl[NC];
    int g = blockIdx.x, t = threadIdx.x;
    for (int i = t; i < 512; i += 256) s2[i] = s2g[g*512 + i];
    __syncthreads();
    {
        float a = bb[t];
        #pragma unroll 8
        for (int d = 0; d < 512; ++d) a += s2[d] * Wb[(size_t)d*256 + t];
        s3[t] = fmaxf(a, 0.f);
    }
    __syncthreads();
    if (t < NC) {
        float a = bo[t];
        #pragma unroll 8
        for (int d = 0; d < 256; ++d) a += s3[d] * Wo[d*NC + t];
        sl[t] = a;
    }
    __syncthreads();
    if (t < 64) {
        float v = (t < NC) ? sl[t] : -3.0e38f;
        float m = v;
        #pragma unroll
        for (int o2 = 32; o2 >= 1; o2 >>= 1) m = fmaxf(m, __shfl_xor(m, o2));
        float e = (t < NC) ? expf(sl[t] - m) : 0.f;
        float s = e;
        #pragma unroll
        for (int o2 = 32; o2 >= 1; o2 >>= 1) s += __shfl_xor(s, o2);
        float ls = logf(s) + m;
        if (t < NC) out[g*NC + t] = sl[t] - ls;
    }
}

// ---------------- launch ----------------
extern "C" void kernel_launch(void* const* d_in, const int* in_sizes, int n_in,
                              void* d_out, int out_size, void* d_ws, size_t ws_size,
                              hipStream_t stream)
{
    const float* pos  = (const float*)d_in[0];
    const float* feat = (const float*)d_in[1];
    const float* W1 = (const float*)d_in[2];
    const float* b1 = (const float*)d_in[3];
    const float* g1 = (const float*)d_in[4];
    const float* be1= (const float*)d_in[5];
    const float* m1 = (const float*)d_in[6];
    const float* v1 = (const float*)d_in[7];
    const float* W2 = (const float*)d_in[8];
    const float* b2 = (const float*)d_in[9];
    const float* g2 = (const float*)d_in[10];
    const float* be2= (const float*)d_in[11];
    const float* m2 = (const float*)d_in[12];
    const float* v2 = (const float*)d_in[13];
    const float* W3 = (const float*)d_in[14];
    const float* b3 = (const float*)d_in[15];
    const float* Wc = (const float*)d_in[16];
    const float* bc = (const float*)d_in[17];
    const float* Wl = (const float*)d_in[18];
    const float* bl = (const float*)d_in[19];
    const float* Wa = (const float*)d_in[20];
    const float* ba = (const float*)d_in[21];
    const float* Wb = (const float*)d_in[22];
    const float* bb = (const float*)d_in[23];
    const float* Wo = (const float*)d_in[24];
    const float* bo = (const float*)d_in[25];
    float* out = (float*)d_out;

    char* ws = (char*)d_ws;
    float* x0  = (float*)(ws + O_X0);
    int*   idx = (int*)  (ws + O_IDX);
    float* x1  = (float*)(ws + O_X1);
    float* uv  = (float*)(ws + O_UV);
    u64*   pk  = (u64*)  (ws + O_UV);   // packed knn partials overlay uv (dead until k_uv)
    float* W1f = (float*)(ws + O_WT);
    float* b1f = W1f + 512;
    float* W2f = b1f + 64;              // (unused by conv1-MFMA; region reserved)
    float* b2f = W2f + 4096;
    float* Wuv = b2f + 64;
    unsigned* out2enc = (unsigned*)(Wuv + 64*256);
    _Float16* Wlh = (_Float16*)(ws + O_WT + 262144);        // 1024x192 fp16 = 384 KB
    float* s2g = (float*)(ws + O_WT + 262144 + 393216);     // 16x512 f32 = 32 KB
    _Float16* W2t = (_Float16*)(ws + O_WT + 262144 + 393216 + 32768);  // 64x64 fp16
    _Float16* W3t = W2t + 4096;                                        // 64x64 fp16

    k_prep <<<450, 256, 0, stream>>>(pos, feat, Wl,
                                     W1,b1,g1,be1,m1,v1, W2,b2,g2,be2,m2,v2, W3, Wc,
                                     x0, Wlh, W1f,b1f,b2f, W2t,W3t, Wuv,out2enc);
    k_knn_part <<<BGRAPH*16*SEG, 256, 0, stream>>>(x0, pk);
    k_knn_merge<<<NPTS/256, 256, 0, stream>>>(pk, idx);
    k_conv1<<<NPTS/CPTS, 256, 0, stream>>>(x0, idx, W1f, b1f, W2t, b2f, W3t, b3, x1);
    k_uv   <<<NPTS/64, 256, 0, stream>>>(x1, Wuv, bc, uv);
    k_x2   <<<NPTS/2, 256, 0, stream>>>(idx, uv);
    dim3 g5(8, 1024);
    k_out1 <<<g5, 256, 0, stream>>>(x1, uv, Wlh, bl, out2enc);
    k_headA<<<BGRAPH*2, 256, 0, stream>>>(out2enc, Wa, ba, s2g);
    k_headB<<<BGRAPH, 256, 0, stream>>>(s2g, Wb, bb, Wo, bo, out);
}